// Round 1
// baseline (570.428 us; speedup 1.0000x reference)
//
#include <hip/hip_runtime.h>

// 2-layer GCN (GraphConv, norm='both') for N=50000, E=1600000, 128->128->40.
// Pipeline: memset degs -> histogram -> scan(row_ptr) -> norms -> CSR fill
//           -> gemm1 (x*norm_src @ W1) -> agg1 (CSR gather-sum, *norm_dst+b1, relu)
//           -> gemm2 (x2*norm_src @ W2) -> agg2 (CSR gather-sum, *norm_dst+b2 -> d_out)

__global__ __launch_bounds__(256) void hist_kernel(const int* __restrict__ src, const int* __restrict__ dst,
                                                   float* deg_src, float* deg_dst, int E) {
    int tid = blockIdx.x * 256 + threadIdx.x;
    if (tid < E) {
        atomicAdd(&deg_src[src[tid]], 1.0f);
        atomicAdd(&deg_dst[dst[tid]], 1.0f);
    }
}

// Single-workgroup exclusive scan of (int)degf[0..N) -> row_ptr[0..N], cursor copy.
__global__ __launch_bounds__(1024) void scan_kernel(const float* __restrict__ degf,
                                                    int* __restrict__ row_ptr,
                                                    int* __restrict__ cursor, int N) {
    __shared__ int wsum[16];
    __shared__ int carry_s;
    int t = threadIdx.x, lane = t & 63, wid = t >> 6;
    if (t == 0) carry_s = 0;
    __syncthreads();
    for (int base = 0; base < N; base += 1024) {
        int i = base + t;
        int v = (i < N) ? (int)degf[i] : 0;
        int x = v;
        #pragma unroll
        for (int off = 1; off < 64; off <<= 1) {
            int y = __shfl_up(x, off, 64);
            if (lane >= off) x += y;
        }
        if (lane == 63) wsum[wid] = x;
        __syncthreads();
        if (wid == 0 && lane < 16) {
            int s = wsum[lane];
            #pragma unroll
            for (int off = 1; off < 16; off <<= 1) {
                int y = __shfl_up(s, off, 64);
                if (lane >= off) s += y;
            }
            wsum[lane] = s;
        }
        __syncthreads();
        int carry = carry_s;
        int woff = (wid == 0) ? 0 : wsum[wid - 1];
        int excl = carry + woff + (x - v);
        if (i < N) { row_ptr[i] = excl; cursor[i] = excl; }
        int total = wsum[15];
        __syncthreads();
        if (t == 0) carry_s = carry + total;
        __syncthreads();
    }
    if (threadIdx.x == 0) row_ptr[N] = carry_s;
}

__global__ __launch_bounds__(256) void norm_kernel(float* deg_src, float* deg_dst, int N) {
    int tid = blockIdx.x * 256 + threadIdx.x;
    if (tid < N) {
        deg_src[tid] = rsqrtf(fmaxf(deg_src[tid], 1.0f));
        deg_dst[tid] = rsqrtf(fmaxf(deg_dst[tid], 1.0f));
    }
}

__global__ __launch_bounds__(256) void fill_kernel(const int* __restrict__ src, const int* __restrict__ dst,
                                                   int* cursor, int* __restrict__ col, int E) {
    int tid = blockIdx.x * 256 + threadIdx.x;
    if (tid < E) {
        int d = dst[tid];
        int pos = atomicAdd(&cursor[d], 1);
        col[pos] = src[tid];
    }
}

// h1[n][jb+j] = norm[n] * sum_k x[n][k] * W[k][jb+j]   (W is 128x128, out cols split in 2 blocks of 64)
__global__ __launch_bounds__(256) void gemm1_kernel(const float* __restrict__ x, const float* __restrict__ norm,
                                                    const float* __restrict__ W, float* __restrict__ out, int N) {
    __shared__ float xs[128 * 32];   // transposed + XOR-swizzled: xs[k*32 + (row ^ sw(k))]
    __shared__ float ws[128 * 64];
    int t = threadIdx.x;
    int rb = blockIdx.x * 32;
    int jb = blockIdx.y * 64;
    #pragma unroll
    for (int i = 0; i < 8; ++i) {                 // W tile: 128x64 = 2048 float4
        int idx = i * 256 + t;
        int k = idx >> 4, j4 = (idx & 15) << 2;
        *(float4*)(ws + k * 64 + j4) = *(const float4*)(W + k * 128 + jb + j4);
    }
    #pragma unroll
    for (int i = 0; i < 4; ++i) {                 // x tile: 32 rows x 128 k = 1024 float4
        int idx = i * 256 + t;
        int row = idx >> 5, m = idx & 31, k4 = m << 2;
        int gr = rb + row;
        float4 v = make_float4(0.f, 0.f, 0.f, 0.f);
        if (gr < N) {
            v = *(const float4*)(x + (size_t)gr * 128 + k4);
            float nm = norm[gr];
            v.x *= nm; v.y *= nm; v.z *= nm; v.w *= nm;
        }
        int r = row ^ ((m & 7) << 2);
        xs[(k4 + 0) * 32 + r] = v.x;
        xs[(k4 + 1) * 32 + r] = v.y;
        xs[(k4 + 2) * 32 + r] = v.z;
        xs[(k4 + 3) * 32 + r] = v.w;
    }
    __syncthreads();
    int jg = t & 15, rg = t >> 4;
    int j = jg << 2, r0 = rg << 1;
    float a00 = 0, a01 = 0, a02 = 0, a03 = 0;
    float a10 = 0, a11 = 0, a12 = 0, a13 = 0;
    #pragma unroll 8
    for (int k = 0; k < 128; ++k) {
        int sw = ((k >> 2) & 7) << 2;
        float2 xv = *(const float2*)&xs[k * 32 + (r0 ^ sw)];
        float4 wv = *(const float4*)&ws[k * 64 + j];
        a00 += xv.x * wv.x; a01 += xv.x * wv.y; a02 += xv.x * wv.z; a03 += xv.x * wv.w;
        a10 += xv.y * wv.x; a11 += xv.y * wv.y; a12 += xv.y * wv.z; a13 += xv.y * wv.w;
    }
    int gr0 = rb + r0;
    if (gr0 < N)     *(float4*)(out + (size_t)gr0 * 128 + jb + j)       = make_float4(a00, a01, a02, a03);
    if (gr0 + 1 < N) *(float4*)(out + (size_t)(gr0 + 1) * 128 + jb + j) = make_float4(a10, a11, a12, a13);
}

// h2[n][j] = norm[n] * sum_k x2[n][k] * W2[k][j]   (W2 is 128x40)
__global__ __launch_bounds__(256) void gemm2_kernel(const float* __restrict__ x, const float* __restrict__ norm,
                                                    const float* __restrict__ W, float* __restrict__ out, int N) {
    __shared__ float xs[128 * 64];
    __shared__ float ws2[128 * 40];
    int t = threadIdx.x;
    int rb = blockIdx.x * 64;
    #pragma unroll
    for (int i = 0; i < 5; ++i) {                 // W2 flat copy: 5120 floats = 1280 float4
        int idx = i * 256 + t;
        *(float4*)(ws2 + idx * 4) = *(const float4*)(W + idx * 4);
    }
    #pragma unroll
    for (int i = 0; i < 8; ++i) {                 // x tile: 64 rows x 128 k = 2048 float4
        int idx = i * 256 + t;
        int row = idx >> 5, m = idx & 31, k4 = m << 2;
        int gr = rb + row;
        float4 v = make_float4(0.f, 0.f, 0.f, 0.f);
        if (gr < N) {
            v = *(const float4*)(x + (size_t)gr * 128 + k4);
            float nm = norm[gr];
            v.x *= nm; v.y *= nm; v.z *= nm; v.w *= nm;
        }
        int r = row ^ ((m & 7) << 2);
        xs[(k4 + 0) * 64 + r] = v.x;
        xs[(k4 + 1) * 64 + r] = v.y;
        xs[(k4 + 2) * 64 + r] = v.z;
        xs[(k4 + 3) * 64 + r] = v.w;
    }
    __syncthreads();
    int jg = t & 7, rg = t >> 3;      // 8 col-groups x 32 row-groups
    int j = jg * 5, r0 = rg << 1;
    float acc0[5] = {0, 0, 0, 0, 0};
    float acc1[5] = {0, 0, 0, 0, 0};
    #pragma unroll 4
    for (int k = 0; k < 128; ++k) {
        int sw = ((k >> 2) & 7) << 2;
        float2 xv = *(const float2*)&xs[k * 64 + (r0 ^ sw)];
        #pragma unroll
        for (int c = 0; c < 5; ++c) {
            float w = ws2[k * 40 + j + c];
            acc0[c] += xv.x * w;
            acc1[c] += xv.y * w;
        }
    }
    int gr0 = rb + r0;
    if (gr0 < N) {
        #pragma unroll
        for (int c = 0; c < 5; ++c) out[(size_t)gr0 * 40 + j + c] = acc0[c];
    }
    if (gr0 + 1 < N) {
        #pragma unroll
        for (int c = 0; c < 5; ++c) out[(size_t)(gr0 + 1) * 40 + j + c] = acc1[c];
    }
}

// One wave per node: sum h1 rows over in-edges, x2 = relu(acc*norm_dst + b1)
__global__ __launch_bounds__(256) void agg1_kernel(const int* __restrict__ row_ptr, const int* __restrict__ col,
                                                   const float* __restrict__ h1, const float* __restrict__ norm_dst,
                                                   const float* __restrict__ b1, float* __restrict__ x2, int N) {
    int n = (blockIdx.x * 256 + threadIdx.x) >> 6;
    int lane = threadIdx.x & 63;
    if (n >= N) return;
    int beg = row_ptr[n], end = row_ptr[n + 1];
    const float2* h = (const float2*)h1;
    float ax = 0.f, ay = 0.f;
    int e = beg;
    for (; e + 4 <= end; e += 4) {
        int s0 = col[e], s1 = col[e + 1], s2 = col[e + 2], s3 = col[e + 3];
        float2 v0 = h[s0 * 64 + lane];
        float2 v1 = h[s1 * 64 + lane];
        float2 v2 = h[s2 * 64 + lane];
        float2 v3 = h[s3 * 64 + lane];
        ax += v0.x; ay += v0.y; ax += v1.x; ay += v1.y;
        ax += v2.x; ay += v2.y; ax += v3.x; ay += v3.y;
    }
    for (; e < end; ++e) {
        int s = col[e];
        float2 v = h[s * 64 + lane];
        ax += v.x; ay += v.y;
    }
    float nd = norm_dst[n];
    float2 b = ((const float2*)b1)[lane];
    float2 o;
    o.x = fmaxf(ax * nd + b.x, 0.f);
    o.y = fmaxf(ay * nd + b.y, 0.f);
    ((float2*)x2)[(size_t)n * 64 + lane] = o;
}

// One wave per node (40 active lanes): out = acc*norm_dst + b2
__global__ __launch_bounds__(256) void agg2_kernel(const int* __restrict__ row_ptr, const int* __restrict__ col,
                                                   const float* __restrict__ h2, const float* __restrict__ norm_dst,
                                                   const float* __restrict__ b2, float* __restrict__ out, int N) {
    int n = (blockIdx.x * 256 + threadIdx.x) >> 6;
    int lane = threadIdx.x & 63;
    if (n >= N) return;
    int beg = row_ptr[n], end = row_ptr[n + 1];
    float acc = 0.f;
    bool act = lane < 40;
    int e = beg;
    for (; e + 4 <= end; e += 4) {
        int s0 = col[e], s1 = col[e + 1], s2 = col[e + 2], s3 = col[e + 3];
        if (act) {
            acc += h2[s0 * 40 + lane];
            acc += h2[s1 * 40 + lane];
            acc += h2[s2 * 40 + lane];
            acc += h2[s3 * 40 + lane];
        }
    }
    for (; e < end; ++e) {
        int s = col[e];
        if (act) acc += h2[s * 40 + lane];
    }
    if (act) out[(size_t)n * 40 + lane] = acc * norm_dst[n] + b2[lane];
}

extern "C" void kernel_launch(void* const* d_in, const int* in_sizes, int n_in,
                              void* d_out, int out_size, void* d_ws, size_t ws_size,
                              hipStream_t stream) {
    const float* x  = (const float*)d_in[0];
    const int* src  = (const int*)d_in[1];
    const int* dst  = (const int*)d_in[2];
    const float* W1 = (const float*)d_in[3];
    const float* b1 = (const float*)d_in[4];
    const float* W2 = (const float*)d_in[5];
    const float* b2 = (const float*)d_in[6];
    float* out = (float*)d_out;

    int N = in_sizes[0] / 128;
    int E = in_sizes[1];
    int NPAD = (N + 63) & ~63;

    float* ws = (float*)d_ws;
    float* deg_src = ws;                               // NPAD floats -> becomes norm_src
    float* deg_dst = ws + NPAD;                        // NPAD floats -> becomes norm_dst
    int* row_ptr   = (int*)(ws + 2 * (size_t)NPAD);    // NPAD+64 ints
    int* cursor    = (int*)(ws + 3 * (size_t)NPAD + 64);
    int* col       = (int*)(ws + 4 * (size_t)NPAD + 64);            // E ints
    float* h1      = ws + 4 * (size_t)NPAD + 64 + E;                // NPAD*128
    float* x2      = h1 + (size_t)NPAD * 128;                       // NPAD*128
    float* h2      = h1;                                            // reuse (h1 dead after agg1)

    hipMemsetAsync(deg_src, 0, (size_t)2 * NPAD * sizeof(float), stream);
    int eb = (E + 255) / 256;
    hist_kernel<<<eb, 256, 0, stream>>>(src, dst, deg_src, deg_dst, E);
    scan_kernel<<<1, 1024, 0, stream>>>(deg_dst, row_ptr, cursor, N);
    norm_kernel<<<(N + 255) / 256, 256, 0, stream>>>(deg_src, deg_dst, N);
    fill_kernel<<<eb, 256, 0, stream>>>(src, dst, cursor, col, E);
    gemm1_kernel<<<dim3((N + 31) / 32, 2), 256, 0, stream>>>(x, deg_src, W1, h1, N);
    agg1_kernel<<<(N * 64 + 255) / 256, 256, 0, stream>>>(row_ptr, col, h1, deg_dst, b1, x2, N);
    gemm2_kernel<<<(N + 63) / 64, 256, 0, stream>>>(x2, deg_src, W2, h2, N);
    agg2_kernel<<<(N * 64 + 255) / 256, 256, 0, stream>>>(row_ptr, col, h2, deg_dst, b2, out, N);
}

// Round 2
// 321.220 us; speedup vs baseline: 1.7758x; 1.7758x over previous
//
#include <hip/hip_runtime.h>

// 2-layer GCN (GraphConv, norm='both') for N=50000, E=1600000, 128->128->40.
// Graph build is a chunked counting sort with NO global atomics:
//   count (LDS hist, packed dst|src) -> reduce (degs+norms) -> scan (row_ptr)
//   -> offsets (per-slice cursors) -> scatter (LDS cursors -> col)
// Then: gemm1 -> agg1 (CSR gather-sum, relu) -> gemm2 -> agg2 -> d_out.

#define CHUNK 16384
#define CHUNK_SHIFT 14
#define NSLICES 64

// Per (chunk, slice) packed histogram: dst count in low 16 bits, src count in high 16.
__global__ __launch_bounds__(256) void count_kernel(const int* __restrict__ src, const int* __restrict__ dst,
                                                    unsigned int* __restrict__ part, int E, int per) {
    __shared__ unsigned int h[CHUNK];
    int c = blockIdx.y, s = blockIdx.x, t = threadIdx.x;
    #pragma unroll
    for (int i = 0; i < CHUNK / 256; ++i) h[i * 256 + t] = 0;
    __syncthreads();
    int base = c << CHUNK_SHIFT;
    int beg = s * per;
    int end = min(E, beg + per);
    int nv = (end - beg) >> 2;
    const int4* d4 = (const int4*)(dst + beg);
    const int4* s4 = (const int4*)(src + beg);
    for (int i = t; i < nv; i += 256) {
        int4 dv = d4[i];
        int4 sv = s4[i];
        int x;
        x = dv.x - base; if ((unsigned)x < CHUNK) atomicAdd(&h[x], 1u);
        x = dv.y - base; if ((unsigned)x < CHUNK) atomicAdd(&h[x], 1u);
        x = dv.z - base; if ((unsigned)x < CHUNK) atomicAdd(&h[x], 1u);
        x = dv.w - base; if ((unsigned)x < CHUNK) atomicAdd(&h[x], 1u);
        x = sv.x - base; if ((unsigned)x < CHUNK) atomicAdd(&h[x], 0x10000u);
        x = sv.y - base; if ((unsigned)x < CHUNK) atomicAdd(&h[x], 0x10000u);
        x = sv.z - base; if ((unsigned)x < CHUNK) atomicAdd(&h[x], 0x10000u);
        x = sv.w - base; if ((unsigned)x < CHUNK) atomicAdd(&h[x], 0x10000u);
    }
    for (int e = beg + (nv << 2) + t; e < end; e += 256) {
        int x = dst[e] - base; if ((unsigned)x < CHUNK) atomicAdd(&h[x], 1u);
        x = src[e] - base;     if ((unsigned)x < CHUNK) atomicAdd(&h[x], 0x10000u);
    }
    __syncthreads();
    unsigned int* out = part + (((size_t)(c * NSLICES + s)) << CHUNK_SHIFT);
    #pragma unroll
    for (int i = 0; i < CHUNK / 256; ++i) out[i * 256 + t] = h[i * 256 + t];
}

// Sum partials per node -> deg_dst (int, for scan) + both norms.
__global__ __launch_bounds__(256) void reduce_kernel(const unsigned int* __restrict__ part,
                                                     float* __restrict__ norm_src, float* __restrict__ norm_dst,
                                                     int* __restrict__ deg_dst_i, int N) {
    int d = blockIdx.x * 256 + threadIdx.x;
    if (d >= N) return;
    int c = d >> CHUNK_SHIFT, idx = d & (CHUNK - 1);
    const unsigned int* p = part + (((size_t)c * NSLICES) << CHUNK_SHIFT) + idx;
    unsigned int dsum = 0, ssum = 0;
    #pragma unroll
    for (int s = 0; s < NSLICES; ++s) {
        unsigned int v = p[(size_t)s << CHUNK_SHIFT];
        dsum += v & 0xFFFFu;
        ssum += v >> 16;
    }
    deg_dst_i[d] = (int)dsum;
    norm_src[d] = rsqrtf(fmaxf((float)ssum, 1.0f));
    norm_dst[d] = rsqrtf(fmaxf((float)dsum, 1.0f));
}

// Single-workgroup exclusive scan of deg[0..N) -> row_ptr[0..N].
__global__ __launch_bounds__(1024) void scan_kernel(const int* __restrict__ deg,
                                                    int* __restrict__ row_ptr, int N) {
    __shared__ int wsum[16];
    __shared__ int carry_s;
    int t = threadIdx.x, lane = t & 63, wid = t >> 6;
    if (t == 0) carry_s = 0;
    __syncthreads();
    for (int base = 0; base < N; base += 1024) {
        int i = base + t;
        int v = (i < N) ? deg[i] : 0;
        int x = v;
        #pragma unroll
        for (int off = 1; off < 64; off <<= 1) {
            int y = __shfl_up(x, off, 64);
            if (lane >= off) x += y;
        }
        if (lane == 63) wsum[wid] = x;
        __syncthreads();
        if (wid == 0 && lane < 16) {
            int s = wsum[lane];
            #pragma unroll
            for (int off = 1; off < 16; off <<= 1) {
                int y = __shfl_up(s, off, 64);
                if (lane >= off) s += y;
            }
            wsum[lane] = s;
        }
        __syncthreads();
        int carry = carry_s;
        int woff = (wid == 0) ? 0 : wsum[wid - 1];
        int excl = carry + woff + (x - v);
        if (i < N) row_ptr[i] = excl;
        int total = wsum[15];
        __syncthreads();
        if (t == 0) carry_s = carry + total;
        __syncthreads();
    }
    if (threadIdx.x == 0) row_ptr[N] = carry_s;
}

// Per node: exclusive scan over slices of dst-counts, in place -> cursors.
__global__ __launch_bounds__(256) void offsets_kernel(unsigned int* __restrict__ part,
                                                      const int* __restrict__ row_ptr, int N) {
    int d = blockIdx.x * 256 + threadIdx.x;
    if (d >= N) return;
    int c = d >> CHUNK_SHIFT, idx = d & (CHUNK - 1);
    unsigned int* p = part + (((size_t)c * NSLICES) << CHUNK_SHIFT) + idx;
    unsigned int running = (unsigned int)row_ptr[d];
    #pragma unroll
    for (int s = 0; s < NSLICES; ++s) {
        unsigned int v = p[(size_t)s << CHUNK_SHIFT];
        p[(size_t)s << CHUNK_SHIFT] = running;
        running += v & 0xFFFFu;
    }
}

// Scatter src ids into CSR col using LDS cursors (no global atomics).
__global__ __launch_bounds__(256) void scatter_kernel(const int* __restrict__ src, const int* __restrict__ dst,
                                                      const unsigned int* __restrict__ cum,
                                                      int* __restrict__ col, int E, int per) {
    __shared__ int cur[CHUNK];
    int c = blockIdx.y, s = blockIdx.x, t = threadIdx.x;
    const unsigned int* cc = cum + (((size_t)(c * NSLICES + s)) << CHUNK_SHIFT);
    #pragma unroll
    for (int i = 0; i < CHUNK / 256; ++i) cur[i * 256 + t] = (int)cc[i * 256 + t];
    __syncthreads();
    int base = c << CHUNK_SHIFT;
    int beg = s * per;
    int end = min(E, beg + per);
    int nv = (end - beg) >> 2;
    const int4* d4 = (const int4*)(dst + beg);
    const int4* s4 = (const int4*)(src + beg);
    for (int i = t; i < nv; i += 256) {
        int4 dv = d4[i];
        int4 sv = s4[i];
        int x;
        x = dv.x - base; if ((unsigned)x < CHUNK) col[atomicAdd(&cur[x], 1)] = sv.x;
        x = dv.y - base; if ((unsigned)x < CHUNK) col[atomicAdd(&cur[x], 1)] = sv.y;
        x = dv.z - base; if ((unsigned)x < CHUNK) col[atomicAdd(&cur[x], 1)] = sv.z;
        x = dv.w - base; if ((unsigned)x < CHUNK) col[atomicAdd(&cur[x], 1)] = sv.w;
    }
    for (int e = beg + (nv << 2) + t; e < end; e += 256) {
        int x = dst[e] - base;
        if ((unsigned)x < CHUNK) col[atomicAdd(&cur[x], 1)] = src[e];
    }
}

// h1[n][jb+j] = norm[n] * sum_k x[n][k] * W[k][jb+j]   (W is 128x128)
__global__ __launch_bounds__(256) void gemm1_kernel(const float* __restrict__ x, const float* __restrict__ norm,
                                                    const float* __restrict__ W, float* __restrict__ out, int N) {
    __shared__ float xs[128 * 32];   // transposed + XOR-swizzled
    __shared__ float ws[128 * 64];
    int t = threadIdx.x;
    int rb = blockIdx.x * 32;
    int jb = blockIdx.y * 64;
    #pragma unroll
    for (int i = 0; i < 8; ++i) {
        int idx = i * 256 + t;
        int k = idx >> 4, j4 = (idx & 15) << 2;
        *(float4*)(ws + k * 64 + j4) = *(const float4*)(W + k * 128 + jb + j4);
    }
    #pragma unroll
    for (int i = 0; i < 4; ++i) {
        int idx = i * 256 + t;
        int row = idx >> 5, m = idx & 31, k4 = m << 2;
        int gr = rb + row;
        float4 v = make_float4(0.f, 0.f, 0.f, 0.f);
        if (gr < N) {
            v = *(const float4*)(x + (size_t)gr * 128 + k4);
            float nm = norm[gr];
            v.x *= nm; v.y *= nm; v.z *= nm; v.w *= nm;
        }
        int r = row ^ ((m & 7) << 2);
        xs[(k4 + 0) * 32 + r] = v.x;
        xs[(k4 + 1) * 32 + r] = v.y;
        xs[(k4 + 2) * 32 + r] = v.z;
        xs[(k4 + 3) * 32 + r] = v.w;
    }
    __syncthreads();
    int jg = t & 15, rg = t >> 4;
    int j = jg << 2, r0 = rg << 1;
    float a00 = 0, a01 = 0, a02 = 0, a03 = 0;
    float a10 = 0, a11 = 0, a12 = 0, a13 = 0;
    #pragma unroll 8
    for (int k = 0; k < 128; ++k) {
        int sw = ((k >> 2) & 7) << 2;
        float2 xv = *(const float2*)&xs[k * 32 + (r0 ^ sw)];
        float4 wv = *(const float4*)&ws[k * 64 + j];
        a00 += xv.x * wv.x; a01 += xv.x * wv.y; a02 += xv.x * wv.z; a03 += xv.x * wv.w;
        a10 += xv.y * wv.x; a11 += xv.y * wv.y; a12 += xv.y * wv.z; a13 += xv.y * wv.w;
    }
    int gr0 = rb + r0;
    if (gr0 < N)     *(float4*)(out + (size_t)gr0 * 128 + jb + j)       = make_float4(a00, a01, a02, a03);
    if (gr0 + 1 < N) *(float4*)(out + (size_t)(gr0 + 1) * 128 + jb + j) = make_float4(a10, a11, a12, a13);
}

// h2[n][j] = norm[n] * sum_k x2[n][k] * W2[k][j]   (W2 is 128x40)
__global__ __launch_bounds__(256) void gemm2_kernel(const float* __restrict__ x, const float* __restrict__ norm,
                                                    const float* __restrict__ W, float* __restrict__ out, int N) {
    __shared__ float xs[128 * 64];
    __shared__ float ws2[128 * 40];
    int t = threadIdx.x;
    int rb = blockIdx.x * 64;
    #pragma unroll
    for (int i = 0; i < 5; ++i) {
        int idx = i * 256 + t;
        *(float4*)(ws2 + idx * 4) = *(const float4*)(W + idx * 4);
    }
    #pragma unroll
    for (int i = 0; i < 8; ++i) {
        int idx = i * 256 + t;
        int row = idx >> 5, m = idx & 31, k4 = m << 2;
        int gr = rb + row;
        float4 v = make_float4(0.f, 0.f, 0.f, 0.f);
        if (gr < N) {
            v = *(const float4*)(x + (size_t)gr * 128 + k4);
            float nm = norm[gr];
            v.x *= nm; v.y *= nm; v.z *= nm; v.w *= nm;
        }
        int r = row ^ ((m & 7) << 2);
        xs[(k4 + 0) * 64 + r] = v.x;
        xs[(k4 + 1) * 64 + r] = v.y;
        xs[(k4 + 2) * 64 + r] = v.z;
        xs[(k4 + 3) * 64 + r] = v.w;
    }
    __syncthreads();
    int jg = t & 7, rg = t >> 3;
    int j = jg * 5, r0 = rg << 1;
    float acc0[5] = {0, 0, 0, 0, 0};
    float acc1[5] = {0, 0, 0, 0, 0};
    #pragma unroll 4
    for (int k = 0; k < 128; ++k) {
        int sw = ((k >> 2) & 7) << 2;
        float2 xv = *(const float2*)&xs[k * 64 + (r0 ^ sw)];
        #pragma unroll
        for (int c = 0; c < 5; ++c) {
            float w = ws2[k * 40 + j + c];
            acc0[c] += xv.x * w;
            acc1[c] += xv.y * w;
        }
    }
    int gr0 = rb + r0;
    if (gr0 < N) {
        #pragma unroll
        for (int c = 0; c < 5; ++c) out[(size_t)gr0 * 40 + j + c] = acc0[c];
    }
    if (gr0 + 1 < N) {
        #pragma unroll
        for (int c = 0; c < 5; ++c) out[(size_t)(gr0 + 1) * 40 + j + c] = acc1[c];
    }
}

// One wave per node: sum h1 rows over in-edges, x2 = relu(acc*norm_dst + b1)
__global__ __launch_bounds__(256) void agg1_kernel(const int* __restrict__ row_ptr, const int* __restrict__ col,
                                                   const float* __restrict__ h1, const float* __restrict__ norm_dst,
                                                   const float* __restrict__ b1, float* __restrict__ x2, int N) {
    int n = (blockIdx.x * 256 + threadIdx.x) >> 6;
    int lane = threadIdx.x & 63;
    if (n >= N) return;
    int beg = row_ptr[n], end = row_ptr[n + 1];
    const float2* h = (const float2*)h1;
    float ax = 0.f, ay = 0.f;
    int e = beg;
    for (; e + 4 <= end; e += 4) {
        int s0 = col[e], s1 = col[e + 1], s2 = col[e + 2], s3 = col[e + 3];
        float2 v0 = h[s0 * 64 + lane];
        float2 v1 = h[s1 * 64 + lane];
        float2 v2 = h[s2 * 64 + lane];
        float2 v3 = h[s3 * 64 + lane];
        ax += v0.x; ay += v0.y; ax += v1.x; ay += v1.y;
        ax += v2.x; ay += v2.y; ax += v3.x; ay += v3.y;
    }
    for (; e < end; ++e) {
        int s = col[e];
        float2 v = h[s * 64 + lane];
        ax += v.x; ay += v.y;
    }
    float nd = norm_dst[n];
    float2 b = ((const float2*)b1)[lane];
    float2 o;
    o.x = fmaxf(ax * nd + b.x, 0.f);
    o.y = fmaxf(ay * nd + b.y, 0.f);
    ((float2*)x2)[(size_t)n * 64 + lane] = o;
}

// One wave per node (40 active lanes): out = acc*norm_dst + b2
__global__ __launch_bounds__(256) void agg2_kernel(const int* __restrict__ row_ptr, const int* __restrict__ col,
                                                   const float* __restrict__ h2, const float* __restrict__ norm_dst,
                                                   const float* __restrict__ b2, float* __restrict__ out, int N) {
    int n = (blockIdx.x * 256 + threadIdx.x) >> 6;
    int lane = threadIdx.x & 63;
    if (n >= N) return;
    int beg = row_ptr[n], end = row_ptr[n + 1];
    float acc = 0.f;
    bool act = lane < 40;
    int e = beg;
    for (; e + 4 <= end; e += 4) {
        int s0 = col[e], s1 = col[e + 1], s2 = col[e + 2], s3 = col[e + 3];
        if (act) {
            acc += h2[s0 * 40 + lane];
            acc += h2[s1 * 40 + lane];
            acc += h2[s2 * 40 + lane];
            acc += h2[s3 * 40 + lane];
        }
    }
    for (; e < end; ++e) {
        int s = col[e];
        if (act) acc += h2[s * 40 + lane];
    }
    if (act) out[(size_t)n * 40 + lane] = acc * norm_dst[n] + b2[lane];
}

extern "C" void kernel_launch(void* const* d_in, const int* in_sizes, int n_in,
                              void* d_out, int out_size, void* d_ws, size_t ws_size,
                              hipStream_t stream) {
    const float* x  = (const float*)d_in[0];
    const int* src  = (const int*)d_in[1];
    const int* dst  = (const int*)d_in[2];
    const float* W1 = (const float*)d_in[3];
    const float* b1 = (const float*)d_in[4];
    const float* W2 = (const float*)d_in[5];
    const float* b2 = (const float*)d_in[6];
    float* out = (float*)d_out;

    int N = in_sizes[0] / 128;
    int E = in_sizes[1];
    int NPAD = (N + 63) & ~63;
    int NCHUNKS = (N + CHUNK - 1) >> CHUNK_SHIFT;
    int per = ((E + NSLICES - 1) / NSLICES + 3) & ~3;

    float* ws = (float*)d_ws;
    float* norm_src = ws;                                  // NPAD floats
    float* norm_dst = ws + NPAD;                           // NPAD floats
    int* deg_dst_i  = (int*)(ws + 2 * (size_t)NPAD);       // NPAD ints
    int* row_ptr    = (int*)(ws + 3 * (size_t)NPAD);       // N+1 ints
    int* col        = (int*)(ws + 4 * (size_t)NPAD + 64);  // E ints
    size_t h1_off   = ((size_t)4 * NPAD + 64 + E + 15) & ~(size_t)15;
    float* h1       = ws + h1_off;                         // NPAD*128 floats
    float* x2       = h1 + (size_t)NPAD * 128;             // NPAD*128 floats
    float* h2       = h1;                                  // reuse (h1 dead after agg1)
    unsigned int* part = (unsigned int*)h1;                // 4M uints, dead before gemm1

    dim3 cgrid(NSLICES, NCHUNKS);
    count_kernel<<<cgrid, 256, 0, stream>>>(src, dst, part, E, per);
    reduce_kernel<<<(N + 255) / 256, 256, 0, stream>>>(part, norm_src, norm_dst, deg_dst_i, N);
    scan_kernel<<<1, 1024, 0, stream>>>(deg_dst_i, row_ptr, N);
    offsets_kernel<<<(N + 255) / 256, 256, 0, stream>>>(part, row_ptr, N);
    scatter_kernel<<<cgrid, 256, 0, stream>>>(src, dst, part, col, E, per);
    gemm1_kernel<<<dim3((N + 31) / 32, 2), 256, 0, stream>>>(x, norm_src, W1, h1, N);
    agg1_kernel<<<(N * 64 + 255) / 256, 256, 0, stream>>>(row_ptr, col, h1, norm_dst, b1, x2, N);
    gemm2_kernel<<<(N + 63) / 64, 256, 0, stream>>>(x2, norm_src, W2, h2, N);
    agg2_kernel<<<(N * 64 + 255) / 256, 256, 0, stream>>>(row_ptr, col, h2, norm_dst, b2, out, N);
}

// Round 3
// 239.179 us; speedup vs baseline: 2.3849x; 1.3430x over previous
//
#include <hip/hip_runtime.h>

// 2-layer GCN (GraphConv, norm='both') for N=50000, E=1600000, 128->128->40.
// Graph build: chunked counting sort, no global atomics.
// Intermediates h1/x2/h2 stored as bf16 (threshold 4.8e-3 allows it) to halve
// the random-gather traffic in agg1/agg2.

#define CHUNK 16384
#define CHUNK_SHIFT 14
#define NSLICES 64

__device__ __forceinline__ unsigned f2bf_bits(float f) {
    unsigned u = __float_as_uint(f);
    return (u + 0x7FFFu + ((u >> 16) & 1u)) >> 16;   // RNE
}
__device__ __forceinline__ unsigned pack_bf2(float a, float b) {
    return f2bf_bits(a) | (f2bf_bits(b) << 16);
}
__device__ __forceinline__ float bflo(unsigned v) { return __uint_as_float(v << 16); }
__device__ __forceinline__ float bfhi(unsigned v) { return __uint_as_float(v & 0xFFFF0000u); }

// ---------------- graph build ----------------

// Per (chunk, slice) packed histogram: dst count low16, src count high16.
__global__ __launch_bounds__(256) void count_kernel(const int* __restrict__ src, const int* __restrict__ dst,
                                                    unsigned int* __restrict__ part, int E, int per) {
    __shared__ unsigned int h[CHUNK];
    int c = blockIdx.y, s = blockIdx.x, t = threadIdx.x;
    #pragma unroll
    for (int i = 0; i < CHUNK / 256; ++i) h[i * 256 + t] = 0;
    __syncthreads();
    int base = c << CHUNK_SHIFT;
    int beg = s * per;
    int end = min(E, beg + per);
    int nv = (end - beg) >> 2;
    const int4* d4 = (const int4*)(dst + beg);
    const int4* s4 = (const int4*)(src + beg);
    for (int i = t; i < nv; i += 256) {
        int4 dv = d4[i];
        int4 sv = s4[i];
        int x;
        x = dv.x - base; if ((unsigned)x < CHUNK) atomicAdd(&h[x], 1u);
        x = dv.y - base; if ((unsigned)x < CHUNK) atomicAdd(&h[x], 1u);
        x = dv.z - base; if ((unsigned)x < CHUNK) atomicAdd(&h[x], 1u);
        x = dv.w - base; if ((unsigned)x < CHUNK) atomicAdd(&h[x], 1u);
        x = sv.x - base; if ((unsigned)x < CHUNK) atomicAdd(&h[x], 0x10000u);
        x = sv.y - base; if ((unsigned)x < CHUNK) atomicAdd(&h[x], 0x10000u);
        x = sv.z - base; if ((unsigned)x < CHUNK) atomicAdd(&h[x], 0x10000u);
        x = sv.w - base; if ((unsigned)x < CHUNK) atomicAdd(&h[x], 0x10000u);
    }
    for (int e = beg + (nv << 2) + t; e < end; e += 256) {
        int x = dst[e] - base; if ((unsigned)x < CHUNK) atomicAdd(&h[x], 1u);
        x = src[e] - base;     if ((unsigned)x < CHUNK) atomicAdd(&h[x], 0x10000u);
    }
    __syncthreads();
    unsigned int* out = part + (((size_t)(c * NSLICES + s)) << CHUNK_SHIFT);
    #pragma unroll
    for (int i = 0; i < CHUNK / 256; ++i) out[i * 256 + t] = h[i * 256 + t];
}

__global__ __launch_bounds__(256) void reduce_kernel(const unsigned int* __restrict__ part,
                                                     float* __restrict__ norm_src, float* __restrict__ norm_dst,
                                                     int* __restrict__ deg_dst_i, int N) {
    int d = blockIdx.x * 256 + threadIdx.x;
    if (d >= N) return;
    int c = d >> CHUNK_SHIFT, idx = d & (CHUNK - 1);
    const unsigned int* p = part + (((size_t)c * NSLICES) << CHUNK_SHIFT) + idx;
    unsigned int dsum = 0, ssum = 0;
    #pragma unroll
    for (int s = 0; s < NSLICES; ++s) {
        unsigned int v = p[(size_t)s << CHUNK_SHIFT];
        dsum += v & 0xFFFFu;
        ssum += v >> 16;
    }
    deg_dst_i[d] = (int)dsum;
    norm_src[d] = rsqrtf(fmaxf((float)ssum, 1.0f));
    norm_dst[d] = rsqrtf(fmaxf((float)dsum, 1.0f));
}

// 3-phase scan: A per-block sums, B 1-wave scan of partials (+row_ptr[N]), C local scan + offset.
__global__ __launch_bounds__(256) void scanA_kernel(const int* __restrict__ deg, int* __restrict__ bsum, int N) {
    __shared__ int wsum[4];
    int b = blockIdx.x, t = threadIdx.x, lane = t & 63, wid = t >> 6;
    int i0 = b * 1024 + t * 4;
    int s = 0;
    if (i0 + 3 < N) {
        int4 v = *(const int4*)(deg + i0);
        s = v.x + v.y + v.z + v.w;
    } else {
        for (int k = 0; k < 4; ++k) { int i = i0 + k; if (i < N) s += deg[i]; }
    }
    #pragma unroll
    for (int off = 32; off; off >>= 1) s += __shfl_down(s, off, 64);
    if (lane == 0) wsum[wid] = s;
    __syncthreads();
    if (t == 0) bsum[b] = wsum[0] + wsum[1] + wsum[2] + wsum[3];
}

__global__ __launch_bounds__(64) void scanB_kernel(int* __restrict__ bsum, int NB,
                                                   int* __restrict__ row_ptr, int N) {
    int t = threadIdx.x;
    int v = (t < NB) ? bsum[t] : 0;
    int x = v;
    #pragma unroll
    for (int off = 1; off < 64; off <<= 1) {
        int y = __shfl_up(x, off, 64);
        if (t >= off) x += y;
    }
    if (t < NB) bsum[t] = x - v;      // exclusive
    if (t == 63) row_ptr[N] = x;      // total == E
}

__global__ __launch_bounds__(256) void scanC_kernel(const int* __restrict__ deg, const int* __restrict__ bsum,
                                                    int* __restrict__ row_ptr, int N) {
    __shared__ int wsum[4];
    int b = blockIdx.x, t = threadIdx.x, lane = t & 63, wid = t >> 6;
    int i0 = b * 1024 + t * 4;
    int4 v = make_int4(0, 0, 0, 0);
    if (i0 + 3 < N) v = *(const int4*)(deg + i0);
    else {
        v.x = (i0 < N) ? deg[i0] : 0;
        v.y = (i0 + 1 < N) ? deg[i0 + 1] : 0;
        v.z = (i0 + 2 < N) ? deg[i0 + 2] : 0;
        v.w = (i0 + 3 < N) ? deg[i0 + 3] : 0;
    }
    int tsum = v.x + v.y + v.z + v.w;
    int x = tsum;
    #pragma unroll
    for (int off = 1; off < 64; off <<= 1) {
        int y = __shfl_up(x, off, 64);
        if (lane >= off) x += y;
    }
    if (lane == 63) wsum[wid] = x;
    __syncthreads();
    int woff = 0;
    for (int k = 0; k < wid; ++k) woff += wsum[k];
    int base = bsum[b] + woff + (x - tsum);
    int e0 = base, e1 = e0 + v.x, e2 = e1 + v.y, e3 = e2 + v.z;
    if (i0 + 3 < N) *(int4*)(row_ptr + i0) = make_int4(e0, e1, e2, e3);
    else {
        if (i0 < N) row_ptr[i0] = e0;
        if (i0 + 1 < N) row_ptr[i0 + 1] = e1;
        if (i0 + 2 < N) row_ptr[i0 + 2] = e2;
        if (i0 + 3 < N) row_ptr[i0 + 3] = e3;
    }
}

__global__ __launch_bounds__(256) void offsets_kernel(unsigned int* __restrict__ part,
                                                      const int* __restrict__ row_ptr, int N) {
    int d = blockIdx.x * 256 + threadIdx.x;
    if (d >= N) return;
    int c = d >> CHUNK_SHIFT, idx = d & (CHUNK - 1);
    unsigned int* p = part + (((size_t)c * NSLICES) << CHUNK_SHIFT) + idx;
    unsigned int running = (unsigned int)row_ptr[d];
    #pragma unroll
    for (int s = 0; s < NSLICES; ++s) {
        unsigned int v = p[(size_t)s << CHUNK_SHIFT];
        p[(size_t)s << CHUNK_SHIFT] = running;
        running += v & 0xFFFFu;
    }
}

__global__ __launch_bounds__(256) void scatter_kernel(const int* __restrict__ src, const int* __restrict__ dst,
                                                      const unsigned int* __restrict__ cum,
                                                      int* __restrict__ col, int E, int per) {
    __shared__ int cur[CHUNK];
    int c = blockIdx.y, s = blockIdx.x, t = threadIdx.x;
    const unsigned int* cc = cum + (((size_t)(c * NSLICES + s)) << CHUNK_SHIFT);
    #pragma unroll
    for (int i = 0; i < CHUNK / 256; ++i) cur[i * 256 + t] = (int)cc[i * 256 + t];
    __syncthreads();
    int base = c << CHUNK_SHIFT;
    int beg = s * per;
    int end = min(E, beg + per);
    int nv = (end - beg) >> 2;
    const int4* d4 = (const int4*)(dst + beg);
    const int4* s4 = (const int4*)(src + beg);
    for (int i = t; i < nv; i += 256) {
        int4 dv = d4[i];
        int4 sv = s4[i];
        int x;
        x = dv.x - base; if ((unsigned)x < CHUNK) col[atomicAdd(&cur[x], 1)] = sv.x;
        x = dv.y - base; if ((unsigned)x < CHUNK) col[atomicAdd(&cur[x], 1)] = sv.y;
        x = dv.z - base; if ((unsigned)x < CHUNK) col[atomicAdd(&cur[x], 1)] = sv.z;
        x = dv.w - base; if ((unsigned)x < CHUNK) col[atomicAdd(&cur[x], 1)] = sv.w;
    }
    for (int e = beg + (nv << 2) + t; e < end; e += 256) {
        int x = dst[e] - base;
        if ((unsigned)x < CHUNK) col[atomicAdd(&cur[x], 1)] = src[e];
    }
}

// ---------------- dense layers ----------------

// h1[n][jb+j] = bf16( norm[n] * sum_k x[n][k] * W[k][jb+j] )
__global__ __launch_bounds__(256) void gemm1_kernel(const float* __restrict__ x, const float* __restrict__ norm,
                                                    const float* __restrict__ W, unsigned short* __restrict__ h1u,
                                                    int N) {
    __shared__ float xs[128 * 32];
    __shared__ float ws[128 * 64];
    int t = threadIdx.x;
    int rb = blockIdx.x * 32;
    int jb = blockIdx.y * 64;
    #pragma unroll
    for (int i = 0; i < 8; ++i) {
        int idx = i * 256 + t;
        int k = idx >> 4, j4 = (idx & 15) << 2;
        *(float4*)(ws + k * 64 + j4) = *(const float4*)(W + k * 128 + jb + j4);
    }
    #pragma unroll
    for (int i = 0; i < 4; ++i) {
        int idx = i * 256 + t;
        int row = idx >> 5, m = idx & 31, k4 = m << 2;
        int gr = rb + row;
        float4 v = make_float4(0.f, 0.f, 0.f, 0.f);
        if (gr < N) {
            v = *(const float4*)(x + (size_t)gr * 128 + k4);
            float nm = norm[gr];
            v.x *= nm; v.y *= nm; v.z *= nm; v.w *= nm;
        }
        int r = row ^ ((m & 7) << 2);
        xs[(k4 + 0) * 32 + r] = v.x;
        xs[(k4 + 1) * 32 + r] = v.y;
        xs[(k4 + 2) * 32 + r] = v.z;
        xs[(k4 + 3) * 32 + r] = v.w;
    }
    __syncthreads();
    int jg = t & 15, rg = t >> 4;
    int j = jg << 2, r0 = rg << 1;
    float a00 = 0, a01 = 0, a02 = 0, a03 = 0;
    float a10 = 0, a11 = 0, a12 = 0, a13 = 0;
    #pragma unroll 8
    for (int k = 0; k < 128; ++k) {
        int sw = ((k >> 2) & 7) << 2;
        float2 xv = *(const float2*)&xs[k * 32 + (r0 ^ sw)];
        float4 wv = *(const float4*)&ws[k * 64 + j];
        a00 += xv.x * wv.x; a01 += xv.x * wv.y; a02 += xv.x * wv.z; a03 += xv.x * wv.w;
        a10 += xv.y * wv.x; a11 += xv.y * wv.y; a12 += xv.y * wv.z; a13 += xv.y * wv.w;
    }
    int gr0 = rb + r0;
    if (gr0 < N) {
        uint2 p = make_uint2(pack_bf2(a00, a01), pack_bf2(a02, a03));
        *(uint2*)(h1u + (size_t)gr0 * 128 + jb + j) = p;
    }
    if (gr0 + 1 < N) {
        uint2 p = make_uint2(pack_bf2(a10, a11), pack_bf2(a12, a13));
        *(uint2*)(h1u + (size_t)(gr0 + 1) * 128 + jb + j) = p;
    }
}

// One wave per node: x2 = bf16(relu(sum h1[src] * norm_dst + b1))
__global__ __launch_bounds__(256) void agg1_kernel(const int* __restrict__ row_ptr, const int* __restrict__ col,
                                                   const unsigned int* __restrict__ h1p, const float* __restrict__ norm_dst,
                                                   const float* __restrict__ b1, unsigned int* __restrict__ x2p, int N) {
    int n = (blockIdx.x * 256 + threadIdx.x) >> 6;
    int lane = threadIdx.x & 63;
    if (n >= N) return;
    int beg = row_ptr[n], end = row_ptr[n + 1];
    float ax = 0.f, ay = 0.f;
    int e = beg;
    for (; e + 4 <= end; e += 4) {
        int s0 = col[e], s1 = col[e + 1], s2 = col[e + 2], s3 = col[e + 3];
        unsigned v0 = h1p[(size_t)s0 * 64 + lane];
        unsigned v1 = h1p[(size_t)s1 * 64 + lane];
        unsigned v2 = h1p[(size_t)s2 * 64 + lane];
        unsigned v3 = h1p[(size_t)s3 * 64 + lane];
        ax += bflo(v0); ay += bfhi(v0);
        ax += bflo(v1); ay += bfhi(v1);
        ax += bflo(v2); ay += bfhi(v2);
        ax += bflo(v3); ay += bfhi(v3);
    }
    for (; e < end; ++e) {
        unsigned v = h1p[(size_t)col[e] * 64 + lane];
        ax += bflo(v); ay += bfhi(v);
    }
    float nd = norm_dst[n];
    float2 b = ((const float2*)b1)[lane];
    float ox = fmaxf(ax * nd + b.x, 0.f);
    float oy = fmaxf(ay * nd + b.y, 0.f);
    x2p[(size_t)n * 64 + lane] = pack_bf2(ox, oy);
}

// h2[n][j] = bf16( norm[n] * sum_k x2[n][k] * W2[k][j] )   (W2 is 128x40)
__global__ __launch_bounds__(256) void gemm2_kernel(const unsigned int* __restrict__ x2p, const float* __restrict__ norm,
                                                    const float* __restrict__ W, unsigned short* __restrict__ h2u, int N) {
    __shared__ float xs[128 * 64];
    __shared__ float ws2[128 * 40];
    int t = threadIdx.x;
    int rb = blockIdx.x * 64;
    #pragma unroll
    for (int i = 0; i < 5; ++i) {
        int idx = i * 256 + t;
        *(float4*)(ws2 + idx * 4) = *(const float4*)(W + idx * 4);
    }
    #pragma unroll
    for (int i = 0; i < 16; ++i) {
        int idx = i * 256 + t;               // 64 rows x 64 k-pairs
        int row = idx >> 6, kp = idx & 63;
        int gr = rb + row;
        unsigned v = 0; float nm = 0.f;
        if (gr < N) {
            v = x2p[(size_t)gr * 64 + kp];
            nm = norm[gr];
        }
        int r = row ^ (((kp >> 1) & 7) << 2);
        xs[(2 * kp + 0) * 64 + r] = bflo(v) * nm;
        xs[(2 * kp + 1) * 64 + r] = bfhi(v) * nm;
    }
    __syncthreads();
    int jg = t & 7, rg = t >> 3;
    int j = jg * 5, r0 = rg << 1;
    float acc0[5] = {0, 0, 0, 0, 0};
    float acc1[5] = {0, 0, 0, 0, 0};
    #pragma unroll 4
    for (int k = 0; k < 128; ++k) {
        int sw = ((k >> 2) & 7) << 2;
        float2 xv = *(const float2*)&xs[k * 64 + (r0 ^ sw)];
        #pragma unroll
        for (int c = 0; c < 5; ++c) {
            float w = ws2[k * 40 + j + c];
            acc0[c] += xv.x * w;
            acc1[c] += xv.y * w;
        }
    }
    int gr0 = rb + r0;
    if (gr0 < N) {
        #pragma unroll
        for (int c = 0; c < 5; ++c) h2u[(size_t)gr0 * 40 + j + c] = (unsigned short)f2bf_bits(acc0[c]);
    }
    if (gr0 + 1 < N) {
        #pragma unroll
        for (int c = 0; c < 5; ++c) h2u[(size_t)(gr0 + 1) * 40 + j + c] = (unsigned short)f2bf_bits(acc1[c]);
    }
}

// One wave per node (40 active lanes): out = sum h2[src] * norm_dst + b2
__global__ __launch_bounds__(256) void agg2_kernel(const int* __restrict__ row_ptr, const int* __restrict__ col,
                                                   const unsigned short* __restrict__ h2u, const float* __restrict__ norm_dst,
                                                   const float* __restrict__ b2, float* __restrict__ out, int N) {
    int n = (blockIdx.x * 256 + threadIdx.x) >> 6;
    int lane = threadIdx.x & 63;
    if (n >= N) return;
    int beg = row_ptr[n], end = row_ptr[n + 1];
    float acc = 0.f;
    bool act = lane < 40;
    int e = beg;
    for (; e + 4 <= end; e += 4) {
        int s0 = col[e], s1 = col[e + 1], s2 = col[e + 2], s3 = col[e + 3];
        if (act) {
            acc += __uint_as_float((unsigned)h2u[(size_t)s0 * 40 + lane] << 16);
            acc += __uint_as_float((unsigned)h2u[(size_t)s1 * 40 + lane] << 16);
            acc += __uint_as_float((unsigned)h2u[(size_t)s2 * 40 + lane] << 16);
            acc += __uint_as_float((unsigned)h2u[(size_t)s3 * 40 + lane] << 16);
        }
    }
    for (; e < end; ++e) {
        int s = col[e];
        if (act) acc += __uint_as_float((unsigned)h2u[(size_t)s * 40 + lane] << 16);
    }
    if (act) out[(size_t)n * 40 + lane] = acc * norm_dst[n] + b2[lane];
}

extern "C" void kernel_launch(void* const* d_in, const int* in_sizes, int n_in,
                              void* d_out, int out_size, void* d_ws, size_t ws_size,
                              hipStream_t stream) {
    const float* x  = (const float*)d_in[0];
    const int* src  = (const int*)d_in[1];
    const int* dst  = (const int*)d_in[2];
    const float* W1 = (const float*)d_in[3];
    const float* b1 = (const float*)d_in[4];
    const float* W2 = (const float*)d_in[5];
    const float* b2 = (const float*)d_in[6];
    float* out = (float*)d_out;

    int N = in_sizes[0] / 128;
    int E = in_sizes[1];
    int NPAD = (N + 63) & ~63;
    int NCHUNKS = (N + CHUNK - 1) >> CHUNK_SHIFT;
    int per = ((E + NSLICES - 1) / NSLICES + 3) & ~3;
    int NB = (N + 1023) / 1024;

    float* ws = (float*)d_ws;
    float* norm_src = ws;                                  // NPAD floats
    float* norm_dst = ws + NPAD;                           // NPAD floats
    int* deg_dst_i  = (int*)(ws + 2 * (size_t)NPAD);       // NPAD ints
    int* row_ptr    = (int*)(ws + 3 * (size_t)NPAD);       // N+1 ints
    int* bsum       = (int*)(ws + 4 * (size_t)NPAD);       // NB (<=64) ints
    int* col        = (int*)(ws + 4 * (size_t)NPAD + 64);  // E ints
    size_t h1_off   = ((size_t)4 * NPAD + 64 + E + 15) & ~(size_t)15;   // float units
    unsigned short* h1u = (unsigned short*)(ws + h1_off);  // NPAD*128 bf16 (12.8MB)
    unsigned int*   h1p = (unsigned int*)h1u;
    unsigned int*   x2p = h1p + (size_t)NPAD * 64;         // NPAD*64 uints (bf16x2)
    unsigned short* h2u = h1u;                             // reuse (h1 dead after agg1)
    unsigned int*   part = (unsigned int*)h1u;             // 16MB, dead before gemm1

    dim3 cgrid(NSLICES, NCHUNKS);
    count_kernel<<<cgrid, 256, 0, stream>>>(src, dst, part, E, per);
    reduce_kernel<<<(N + 255) / 256, 256, 0, stream>>>(part, norm_src, norm_dst, deg_dst_i, N);
    scanA_kernel<<<NB, 256, 0, stream>>>(deg_dst_i, bsum, N);
    scanB_kernel<<<1, 64, 0, stream>>>(bsum, NB, row_ptr, N);
    scanC_kernel<<<NB, 256, 0, stream>>>(deg_dst_i, bsum, row_ptr, N);
    offsets_kernel<<<(N + 255) / 256, 256, 0, stream>>>(part, row_ptr, N);
    scatter_kernel<<<cgrid, 256, 0, stream>>>(src, dst, part, col, E, per);
    gemm1_kernel<<<dim3((N + 31) / 32, 2), 256, 0, stream>>>(x, norm_src, W1, h1u, N);
    agg1_kernel<<<(N * 64 + 255) / 256, 256, 0, stream>>>(row_ptr, col, h1p, norm_dst, b1, x2p, N);
    gemm2_kernel<<<(N + 63) / 64, 256, 0, stream>>>(x2p, norm_src, W2, h2u, N);
    agg2_kernel<<<(N * 64 + 255) / 256, 256, 0, stream>>>(row_ptr, col, h2u, norm_dst, b2, out, N);
}